// Round 2
// baseline (244.473 us; speedup 1.0000x reference)
//
#include <hip/hip_runtime.h>
#include <math.h>

#define Bn 32
#define Pn 256
#define Wn 16
#define Cn 64
#define Hn 128
#define PREDn 64
#define TOKn 17

// ---------------- Kernel A: logstd anchor (mean over P of log(max(std,1e-3))) ----------------
// One block per b; 256 threads = 64 c x 4 partial-sums.
__global__ void lsa_kernel(const float* __restrict__ std_hist,
                           float* __restrict__ lsa) {
  int b = blockIdx.x;
  int c = threadIdx.x & 63;
  int q = threadIdx.x >> 6;  // 0..3
  const float* base = std_hist + ((size_t)b * Pn) * Cn + c;
  float s = 0.f;
#pragma unroll
  for (int i = 0; i < 64; ++i) {
    int t = q + 4 * i;
    s += logf(fmaxf(base[(size_t)t * Cn], 1e-3f));
  }
  __shared__ float red[4][64];
  red[q][c] = s;
  __syncthreads();
  if (q == 0) {
    lsa[b * 64 + c] =
        (red[0][c] + red[1][c] + red[2][c] + red[3][c]) * (1.0f / 256.0f);
  }
}

// ---------------- Kernel B: token matmul + EMA (the hot kernel) ----------------
// block: 256 thr covers 32 c x 64 hh for one (b, branch, P-half).
// thread: c = cblk*32 + (tid&31), hh = hblk*64 + (tid>>5)*8 + i (8 hh per thread, W in regs)
__launch_bounds__(256, 2)
__global__ void ema_kernel(
    const float* __restrict__ mu_hist, const float* __restrict__ std_hist,
    const float* __restrict__ anchor, const float* __restrict__ raw,
    const float* __restrict__ mW, const float* __restrict__ mb, const float* __restrict__ mal,
    const float* __restrict__ sW, const float* __restrict__ sb, const float* __restrict__ sal,
    const float* __restrict__ lsa, float* __restrict__ Spart) {
  const int sx = blockIdx.x;
  const int cblk = sx & 1, hblk = (sx >> 1) & 1, ph = (sx >> 2) & 1;
  const int b = blockIdx.y, br = blockIdx.z;
  const int tid = threadIdx.x;
  const int cr = tid & 31;
  const int hhg = tid >> 5;  // 0..7

  const float* inW = br ? sW : mW;
  const float* inb = br ? sb : mb;
  const float* alog = br ? sal : mal;
  const int hh0 = hblk * 64 + hhg * 8;

  // preload W columns into registers: 17 x 8
  float Wr[TOKn][8];
#pragma unroll
  for (int k = 0; k < TOKn; ++k) {
    float4 w0 = *(const float4*)&inW[k * Hn + hh0];
    float4 w1 = *(const float4*)&inW[k * Hn + hh0 + 4];
    Wr[k][0] = w0.x; Wr[k][1] = w0.y; Wr[k][2] = w0.z; Wr[k][3] = w0.w;
    Wr[k][4] = w1.x; Wr[k][5] = w1.y; Wr[k][6] = w1.z; Wr[k][7] = w1.w;
  }
  float av[8], oma[8], bias[8], h[8];
#pragma unroll
  for (int i = 0; i < 8; ++i) {
    float a = 1.0f / (1.0f + expf(-alog[hh0 + i]));
    av[i] = a; oma[i] = 1.0f - a; bias[i] = inb[hh0 + i]; h[i] = 0.0f;
  }

  const int cs = cblk * 32 + cr;  // this thread's c (compute + raw staging)
  const size_t bP = (size_t)b * Pn;
  const float* rawb = raw + bP * Wn * Cn;
  const float* mub = mu_hist + bP * Cn;
  const float* stdb = std_hist + bP * Cn;
  const float anch_cs = anchor[b * Cn + cs];
  float anch2 = 0.f, lsa2 = 0.f;
  if (tid < 32) {
    anch2 = anchor[b * Cn + cblk * 32 + tid];
    lsa2 = lsa[b * Cn + cblk * 32 + tid];
  }

  __shared__ float tok[2][32][20];  // double-buffered token rows, stride 20 floats

  const int w0 = tid >> 5;  // 0..7 (two w's per thread: w0, w0+8)
  const int t0 = ph * 128;

  auto stage = [&](int t, int buf) {
    const float* rawt = rawb + (size_t)t * (Wn * Cn);
    if (br == 0) {
      float r0 = rawt[w0 * Cn + cs];
      float r1 = rawt[(w0 + 8) * Cn + cs];
      tok[buf][cr][1 + w0] = r0 - anch_cs;
      tok[buf][cr][1 + w0 + 8] = r1 - anch_cs;
      if (tid < 32) {
        tok[buf][tid][0] = mub[(size_t)t * Cn + cblk * 32 + tid] - anch2;
      }
    } else {
      float mu = mub[(size_t)t * Cn + cs];
      float sd = stdb[(size_t)t * Cn + cs];
      float inv = 1.0f / (sd + 1e-5f);
      float r0 = rawt[w0 * Cn + cs];
      float r1 = rawt[(w0 + 8) * Cn + cs];
      tok[buf][cr][1 + w0] = (r0 - mu) * inv;
      tok[buf][cr][1 + w0 + 8] = (r1 - mu) * inv;
      if (tid < 32) {
        float sv = stdb[(size_t)t * Cn + cblk * 32 + tid];
        tok[buf][tid][0] = logf(fmaxf(sv, 1e-3f)) - lsa2;
      }
    }
  };

  stage(t0, 0);
  __syncthreads();
  int cur = 0;
  for (int tt = 0; tt < 128; ++tt) {
    if (tt + 1 < 128) stage(t0 + tt + 1, cur ^ 1);
    const float* row = &tok[cur][cr][0];
    float4 q0 = *(const float4*)(row);
    float4 q1 = *(const float4*)(row + 4);
    float4 q2 = *(const float4*)(row + 8);
    float4 q3 = *(const float4*)(row + 12);
    float q4 = row[16];
#pragma unroll
    for (int i = 0; i < 8; ++i) {
      float u = bias[i];
      u = fmaf(q0.x, Wr[0][i], u);
      u = fmaf(q0.y, Wr[1][i], u);
      u = fmaf(q0.z, Wr[2][i], u);
      u = fmaf(q0.w, Wr[3][i], u);
      u = fmaf(q1.x, Wr[4][i], u);
      u = fmaf(q1.y, Wr[5][i], u);
      u = fmaf(q1.z, Wr[6][i], u);
      u = fmaf(q1.w, Wr[7][i], u);
      u = fmaf(q2.x, Wr[8][i], u);
      u = fmaf(q2.y, Wr[9][i], u);
      u = fmaf(q2.z, Wr[10][i], u);
      u = fmaf(q2.w, Wr[11][i], u);
      u = fmaf(q3.x, Wr[12][i], u);
      u = fmaf(q3.y, Wr[13][i], u);
      u = fmaf(q3.z, Wr[14][i], u);
      u = fmaf(q3.w, Wr[15][i], u);
      u = fmaf(q4, Wr[16][i], u);
      h[i] = fmaf(av[i], h[i], oma[i] * u);  // EMA step: a*h + (1-a)*u
    }
    __syncthreads();
    cur ^= 1;
  }

  // write chunk-EMA result, thread-contiguous (coalesced float4 x2)
  const int idx_block = (((br * 2 + ph) * Bn + b) * 2 + cblk) * 2 + hblk;
  float* op = Spart + (size_t)idx_block * 2048 + tid * 8;
  float4 o0 = {h[0], h[1], h[2], h[3]};
  float4 o1 = {h[4], h[5], h[6], h[7]};
  *(float4*)op = o0;
  *(float4*)(op + 4) = o1;
}

// ---------------- Kernel C: combine chunks + GELU-MLP head + output ----------------
__launch_bounds__(128, 4)
__global__ void head_kernel(
    const float* __restrict__ anchor, const float* __restrict__ lsa,
    const float* __restrict__ mal, const float* __restrict__ mpW, const float* __restrict__ mpb,
    const float* __restrict__ moW, const float* __restrict__ mob, const float* __restrict__ gmu,
    const float* __restrict__ sal, const float* __restrict__ spW, const float* __restrict__ spb,
    const float* __restrict__ soW, const float* __restrict__ sob, const float* __restrict__ gst,
    const float* __restrict__ Spart, float* __restrict__ out) {
  const int br = blockIdx.y;
  const int bc0 = blockIdx.x * 8;  // 8 (b,c) rows per block
  const int tid = threadIdx.x;     // 0..127 = hh
  const float* alog = br ? sal : mal;
  const float* pW = br ? spW : mpW;
  const float* pb = br ? spb : mpb;
  const float* oW = br ? soW : moW;
  const float* ob = br ? sob : mob;

  __shared__ float smem[2048];  // [0,1024): gelu then reduce; [1024,2048): h2
  float* g_lds = smem;
  float* h2 = smem + 1024;

  const float a = 1.0f / (1.0f + expf(-alog[tid]));
  float ap = a;  // a^128 via 7 squarings
#pragma unroll
  for (int s7 = 0; s7 < 7; ++s7) ap *= ap;

  const int hblk = tid >> 6;
  const int hhg = (tid >> 3) & 7;
  const int ii = tid & 7;

  float hreg[8];
#pragma unroll
  for (int g = 0; g < 8; ++g) {
    int bc = bc0 + g;
    int bb = bc >> 6, cc = bc & 63;
    int cblk2 = cc >> 5, crr = cc & 31;
    size_t base0 = ((size_t)((((br * 2 + 0) * Bn + bb) * 2 + cblk2) * 2 + hblk)) * 2048 +
                   (hhg * 32 + crr) * 8 + ii;
    size_t base1 = ((size_t)((((br * 2 + 1) * Bn + bb) * 2 + cblk2) * 2 + hblk)) * 2048 +
                   (hhg * 32 + crr) * 8 + ii;
    float hv = fmaf(ap, Spart[base0], Spart[base1]);  // exact chunk composition
    hreg[g] = hv;
    g_lds[g * 128 + tid] = 0.5f * hv * (1.0f + erff(hv * 0.70710678118654752f));
  }
  __syncthreads();

  float acc[8];
#pragma unroll
  for (int g = 0; g < 8; ++g) acc[g] = hreg[g] + pb[tid];
  for (int j = 0; j < 128; ++j) {
    float wv = pW[j * Hn + tid];
#pragma unroll
    for (int g = 0; g < 8; ++g) acc[g] = fmaf(g_lds[g * 128 + j], wv, acc[g]);
  }
#pragma unroll
  for (int g = 0; g < 8; ++g) h2[g * 128 + tid] = acc[g];
  __syncthreads();

  // out projection: p = tid&63, j-half = tid>>6
  const int p = tid & 63;
  const int jh = tid >> 6;
  float s[8];
#pragma unroll
  for (int g = 0; g < 8; ++g) s[g] = 0.f;
  for (int j = jh * 64; j < jh * 64 + 64; ++j) {
    float wv = oW[j * PREDn + p];
#pragma unroll
    for (int g = 0; g < 8; ++g) s[g] = fmaf(h2[g * 128 + j], wv, s[g]);
  }
  float* red = smem;  // reuse g_lds region (no longer read)
#pragma unroll
  for (int g = 0; g < 8; ++g) red[jh * 512 + g * 64 + p] = s[g];
  __syncthreads();
  if (tid < 64) {
#pragma unroll
    for (int g = 0; g < 8; ++g) {
      int bc = bc0 + g;
      int bb = bc >> 6, cc = bc & 63;
      float tot = red[g * 64 + p] + red[512 + g * 64 + p] + ob[p];
      if (br == 0) {
        out[((size_t)bb * PREDn + p) * Cn + cc] = fmaf(gmu[cc], tot, anchor[bb * Cn + cc]);
      } else {
        float lf = fmaf(gst[cc], tot, lsa[bb * Cn + cc]);
        out[131072 + ((size_t)bb * PREDn + p) * Cn + cc] = fmaxf(expf(lf), 1e-3f);
      }
    }
  }
}

extern "C" void kernel_launch(void* const* d_in, const int* in_sizes, int n_in,
                              void* d_out, int out_size, void* d_ws, size_t ws_size,
                              hipStream_t stream) {
  (void)in_sizes; (void)n_in; (void)out_size; (void)ws_size;
  const float* mu_hist = (const float*)d_in[0];
  const float* std_hist = (const float*)d_in[1];
  const float* anchor = (const float*)d_in[2];
  const float* raw = (const float*)d_in[3];
  const float* mW = (const float*)d_in[4];
  const float* mb_ = (const float*)d_in[5];
  const float* mal = (const float*)d_in[6];
  const float* mpW = (const float*)d_in[7];
  const float* mpb = (const float*)d_in[8];
  const float* moW = (const float*)d_in[9];
  const float* mob = (const float*)d_in[10];
  const float* gmu = (const float*)d_in[11];
  const float* sW = (const float*)d_in[12];
  const float* sb_ = (const float*)d_in[13];
  const float* sal = (const float*)d_in[14];
  const float* spW = (const float*)d_in[15];
  const float* spb = (const float*)d_in[16];
  const float* soW = (const float*)d_in[17];
  const float* sob = (const float*)d_in[18];
  const float* gst = (const float*)d_in[19];
  float* out = (float*)d_out;
  float* ws = (float*)d_ws;

  float* lsa = ws;                 // 2048 floats
  float* Spart = ws + 2048;        // 2*2*32*2*2*2048 = 1048576 floats (~4.2 MB total ws)

  hipLaunchKernelGGL(lsa_kernel, dim3(32), dim3(256), 0, stream, std_hist, lsa);
  hipLaunchKernelGGL(ema_kernel, dim3(8, 32, 2), dim3(256), 0, stream,
                     mu_hist, std_hist, anchor, raw, mW, mb_, mal, sW, sb_, sal, lsa, Spart);
  hipLaunchKernelGGL(head_kernel, dim3(256, 2), dim3(128), 0, stream,
                     anchor, lsa, mal, mpW, mpb, moW, mob, gmu,
                     sal, spW, spb, soW, sob, gst, Spart, out);
}